// Round 1
// baseline (427.591 us; speedup 1.0000x reference)
//
#include <hip/hip_runtime.h>

typedef float  floatx4 __attribute__((ext_vector_type(4)));
typedef float  float4a __attribute__((ext_vector_type(4), aligned(4)));
typedef short  short8  __attribute__((ext_vector_type(8)));
typedef short  short4v __attribute__((ext_vector_type(4)));
typedef int    intx4   __attribute__((ext_vector_type(4)));

#define NB   32
#define NC   512
#define NHW  3136

template<int N> struct IC { static constexpr int value = N; };

// resample map: p//7*6 + min(p%7,5)
__device__ __forceinline__ int ridx(int p) {
    int q = p / 7;
    int r = p - q * 7;
    return q * 6 + (r < 5 ? r : 5);
}
__device__ __forceinline__ short f2bf(float f) {
    unsigned int x = __builtin_bit_cast(unsigned int, f);
    x += 0x7fffu + ((x >> 16) & 1u);           // RNE
    return (short)(x >> 16);
}
__device__ __forceinline__ void gload_lds16(const void* g, void* l) {
    __builtin_amdgcn_global_load_lds(
        (const __attribute__((address_space(1))) unsigned int*)g,
        (__attribute__((address_space(3))) unsigned int*)l, 16, 0, 0);
}

// ---- pre-pass: conv_w f32 -> bf16 with BN scale FOLDED IN (sc>0 since gamma>0);
//      pbg[c] = shift/scale = beta/sc - mean, so h = relu(x + t) and W' = W*sc ----
__global__ __launch_bounds__(256)
void prep_kernel(const float* __restrict__ w,
                 const float* __restrict__ g_, const float* __restrict__ be_,
                 const float* __restrict__ mn_, const float* __restrict__ vr_,
                 short* __restrict__ wb, float* __restrict__ pbg)
{
    int id = (blockIdx.x * 256 + threadIdx.x) * 4;   // 256 blocks x 256 thr x 4 = 262144
    int c  = id & 1023;                              // channel of these 4 elements
    float4a v  = *(const float4a*)(w + id);
    float4a gg = *(const float4a*)(g_ + c);
    float4a vr = *(const float4a*)(vr_ + c);
    short4v s;
#pragma unroll
    for (int j = 0; j < 4; ++j) {
        float sc = gg[j] * rsqrtf(vr[j] + 1e-5f);
        s[j] = f2bf(v[j] * sc);
    }
    *(short4v*)(wb + id) = s;
    if (blockIdx.x == 0) {
        for (int cc2 = threadIdx.x; cc2 < 1024; cc2 += 256) {
            float sc = g_[cc2] * rsqrtf(vr_[cc2] + 1e-5f);
            pbg[cc2] = be_[cc2] / sc - mn_[cc2];
        }
    }
}

// Tile: M=128 spatial slots (112 real: rows 2ph,2ph+1), N=128 out-ch, BK=64.
// Double-buffered LDS, 1 barrier/kc; Wt via async global_load_lds (src-swizzled);
// x prefetched into registers DEPTH-2 (issued after the barrier, consumed 2 kc later).
// blockIdx XCD-chunk-swizzled so the nt=0/1 pair of each site shares one XCD's L2.
__global__ __launch_bounds__(256, 2)
void fused_bn_conv_pool(const float* __restrict__ x,
                        const float* __restrict__ pbg,
                        const short* __restrict__ wgt,
                        float* __restrict__ out)
{
    __shared__ char smem[65536];
    short* WtB[2] = { (short*)(smem),         (short*)(smem + 32768) };
    short* AtB[2] = { (short*)(smem + 16384), (short*)(smem + 49152) };
    float* ys = (float*)smem;                  // [32][132] f32 epilogue (overlaps buf0)

    const int t    = threadIdx.x;
    // ---- XCD-aware swizzle: grid 1792 = 8 XCDs x 224. Physical bx0 -> logical bx
    //      so logical-consecutive blocks (incl. each site's nt-pair) land on ONE XCD.
    const int bx0  = blockIdx.x;
    const int bx   = (bx0 & 7) * 224 + (bx0 >> 3);
    const int site = bx >> 1;
    const int nt   = bx & 1;                    // o-half: [nt*128, nt*128+128)
    const int b    = site / 28;
    const int ph   = site - b * 28;

    // ---- staging mapping: thread owns 8 consecutive channels (cc) x 4 m (mg) ----
    const int cc     = t & 7;                   // k-octet within BK
    const int mg     = t >> 3;                  // 0..31
    const int m_base = mg * 4;                  // 0..124
    const bool realm = (m_base < 112);
    const int rr = (m_base >= 56) ? 1 : 0;      // row within pair
    const int w0 = m_base - rr * 56;
    const int hs = 4 + ridx(2 * ph + rr);       // gather source row
    const int c0 = ridx(w0);                    // gather base col (cols c0..c0+3 cover all 4)
    const int offg = hs * 56 + 4 + c0;
    int d_[4];
#pragma unroll
    for (int j = 0; j < 4; ++j) d_[j] = ridx(w0 + j) - c0;   // 0..3
    const int xb   = b * NC * NHW;
    const int offd = 112 * ph + m_base;         // h*56+w == 112*ph+m (linear!)

    // ---- MFMA mapping ----
    const int lid = t & 63;
    const int wv  = t >> 6;
    const int wo  = wv & 1;
    const int wm  = wv >> 1;
    const int col = lid & 15;
    const int q4  = lid >> 4;
    const int obw = wo * 64;
    const int mbw = wm * 64;
    const int sw  = col & 7;                    // read-side chunk swizzle key

    floatx4 acc[4][4];
#pragma unroll
    for (int i = 0; i < 4; ++i)
#pragma unroll
        for (int j = 0; j < 4; ++j)
            acc[i][j] = (floatx4){0.f, 0.f, 0.f, 0.f};

    const short* wrow = wgt + nt * 128 * 1024;

    // ---- depth-2 prefetch registers: pf[set][8 channels] of raw x f32 ----
    float4a pf[2][8];

    auto load_into = [&](int kc, auto ic) {
        constexpr int S = decltype(ic)::value;
        if (!realm) return;
        const int k0 = kc * 64;
        const int cb = k0 + cc * 8;
        if (k0 < 512) {
#pragma unroll
            for (int i = 0; i < 8; ++i)
                pf[S][i] = *(const float4a*)(x + xb + (cb + i) * NHW + offd);
        } else {
#pragma unroll
            for (int i = 0; i < 8; ++i)
                pf[S][i] = *(const float4a*)(x + xb + (cb + i - 512) * NHW + offg);
        }
    };

    auto body = [&](int kc, short* Wt, short* At, auto ic) {
        constexpr int S = decltype(ic)::value;
        const int k0 = kc * 64;
        const int cb = k0 + cc * 8;
        // ---- async-DMA Wt for this kc (source-side XOR swizzle: slot s holds seg s^(o&7)) ----
#pragma unroll
        for (int it = 0; it < 4; ++it) {
            int q = it * 256 + t;
            int o = q >> 3, sl = q & 7;
            gload_lds16(wrow + o * 1024 + k0 + ((sl ^ (o & 7)) * 8), Wt + q * 8);
        }
        // ---- transform pf[S] -> bf16 At[m][k]: relu(x + t[c]) then packed-RNE cvt ----
        {
            const bool upper = (k0 >= 512);
            intx4 vj[4];
#pragma unroll
            for (int j = 0; j < 4; ++j) vj[j] = (intx4){0, 0, 0, 0};
            if (realm) {
                float4a tLo = *(const float4a*)(pbg + cb);
                float4a tHi = *(const float4a*)(pbg + cb + 4);
                float rprev[4];
#pragma unroll
                for (int i = 0; i < 8; ++i) {
                    const float tch = (i < 4) ? tLo[i] : tHi[i - 4];
                    float vv[4];
                    if (!upper) {
#pragma unroll
                        for (int j = 0; j < 4; ++j) vv[j] = pf[S][i][j];
                    } else {
#pragma unroll
                        for (int j = 0; j < 4; ++j) {
                            int dd = d_[j];
                            float a  = (dd >= 2) ? pf[S][i][2] : pf[S][i][0];
                            float bq = (dd >= 2) ? pf[S][i][3] : pf[S][i][1];
                            vv[j] = (dd & 1) ? bq : a;
                        }
                    }
                    if (!(i & 1)) {
#pragma unroll
                        for (int j = 0; j < 4; ++j) rprev[j] = fmaxf(vv[j] + tch, 0.f);
                    } else {
#pragma unroll
                        for (int j = 0; j < 4; ++j) {
                            float rc = fmaxf(vv[j] + tch, 0.f);
                            unsigned pk;
                            asm("v_cvt_pk_bf16_f32 %0, %1, %2"
                                : "=v"(pk) : "v"(rprev[j]), "v"(rc));
                            vj[j][i >> 1] = (int)pk;
                        }
                    }
                }
            }
#pragma unroll
            for (int j = 0; j < 4; ++j) {
                int m = m_base + j;
                *(intx4*)(At + m * 64 + ((cc ^ (m & 7)) * 8)) = vj[j];
            }
        }
        __syncthreads();          // drains Wt DMA; At visible; prev MFMA's buf now free

        // ---- prefetch kc+2's x into the set just consumed (in flight across MFMA
        //      AND the whole next body -> ~2x the latency window of depth-1) ----
        if (kc < 14) load_into(kc + 2, ic);

        // ---- MFMA: D[o][m] += Wt * At ----
#pragma unroll
        for (int ks = 0; ks < 2; ++ks) {
            const int cb2 = ks * 4 + q4;
            short8 af[4], bf[4];
#pragma unroll
            for (int of = 0; of < 4; ++of) {
                int row = obw + of * 16 + col;
                af[of] = *(const short8*)(Wt + row * 64 + ((cb2 ^ sw) * 8));
            }
#pragma unroll
            for (int mf = 0; mf < 4; ++mf) {
                int row = mbw + mf * 16 + col;
                bf[mf] = *(const short8*)(At + row * 64 + ((cb2 ^ sw) * 8));
            }
#pragma unroll
            for (int of = 0; of < 4; ++of)
#pragma unroll
                for (int mf = 0; mf < 4; ++mf)
                    acc[of][mf] = __builtin_amdgcn_mfma_f32_16x16x32_bf16(
                        af[of], bf[mf], acc[of][mf], 0, 0, 0);
        }
        // no second barrier: double-buffered
    };

    // prologue: two sets in flight before the first transform
    load_into(0, IC<0>{});
    load_into(1, IC<1>{});

    for (int kc2 = 0; kc2 < 16; kc2 += 2) {
        body(kc2,     WtB[0], AtB[0], IC<0>{});
        body(kc2 + 1, WtB[1], AtB[1], IC<1>{});
    }

    __syncthreads();   // all waves done with buf1 reads before ys (overlaps buf0) reuse

    // ---- epilogue: 4 slices of 32 o; acc -> LDS f32 -> 2x2 pool -> f32 out ----
    // fully unrolled: acc[][] indices must stay compile-time (R2 lesson: scratch demotion)
#pragma unroll
    for (int s = 0; s < 4; ++s) {
        if (wo == (s >> 1)) {
#pragma unroll
            for (int of2 = 0; of2 < 2; ++of2) {
                const int of  = (s & 1) * 2 + of2;
                const int olb = of2 * 16 + q4 * 4;   // o within slice (row = q*4+reg)
#pragma unroll
                for (int mf = 0; mf < 4; ++mf) {
                    const int m = mbw + mf * 16 + col;
#pragma unroll
                    for (int rg = 0; rg < 4; ++rg)
                        ys[(olb + rg) * 132 + m] = acc[of][mf][rg];
                }
            }
        }
        __syncthreads();
        for (int i = t; i < 896; i += 256) {
            int ol = i / 28;
            int pw = i - ol * 28;
            const float* yr = ys + ol * 132 + 2 * pw;
            float v = (yr[0] + yr[1] + yr[56] + yr[57]) * 0.25f;
            int og = nt * 128 + s * 32 + ol;
            out[((b * 256 + og) * 28 + ph) * 28 + pw] = v;
        }
        __syncthreads();
    }
}

extern "C" void kernel_launch(void* const* d_in, const int* in_sizes, int n_in,
                              void* d_out, int out_size, void* d_ws, size_t ws_size,
                              hipStream_t stream) {
    (void)in_sizes; (void)n_in; (void)out_size; (void)ws_size;
    const float* x  = (const float*)d_in[0];
    const float* g  = (const float*)d_in[1];
    const float* be = (const float*)d_in[2];
    const float* mn = (const float*)d_in[3];
    const float* vr = (const float*)d_in[4];
    const float* w  = (const float*)d_in[5];
    float* o   = (float*)d_out;
    short* wb  = (short*)d_ws;                        // 512 KB bf16 folded weights
    float* pbg = (float*)((char*)d_ws + 524288);      // 4 KB folded BN shift (t = beta/sc - mean)

    prep_kernel<<<dim3(256), dim3(256), 0, stream>>>(w, g, be, mn, vr, wb, pbg);
    fused_bn_conv_pool<<<dim3(32 * 28 * 2), dim3(256), 0, stream>>>(x, pbg, wb, o);
}